// Round 1
// baseline (1640.447 us; speedup 1.0000x reference)
//
#include <hip/hip_runtime.h>
#include <math.h>

#define SDIM 224
#define KTOP 10
#define NB 2
#define NV 5023
#define NF 5000
#define FST 24          // floats per preprocessed face struct
#define BLUR 1e-4f
#define IMG_SZ (NB * SDIM * SDIM)   // 100352

// Exact (numpy-op-order) point-segment distance^2, matching _edge_d2:
// t = clip(dot(ap,ab)/max(dot(ab,ab),1e-12), 0, 1); proj = a + t*ab; |p-proj|^2
__device__ __forceinline__ float seg_d2_exact(float ax, float ay, float abx, float aby,
                                              float L, float px, float py) {
    float apx = __fsub_rn(px, ax), apy = __fsub_rn(py, ay);
    float dot = __fadd_rn(__fmul_rn(apx, abx), __fmul_rn(apy, aby));
    float t = __fdiv_rn(dot, L);
    t = fminf(fmaxf(t, 0.0f), 1.0f);
    float prx = __fadd_rn(ax, __fmul_rn(t, abx));
    float pry = __fadd_rn(ay, __fmul_rn(t, aby));
    float dx = __fsub_rn(px, prx), dy = __fsub_rn(py, pry);
    return __fadd_rn(__fmul_rn(dx, dx), __fmul_rn(dy, dy));
}

__global__ void preprocess_kernel(const float* __restrict__ verts,
                                  const int* __restrict__ faces,
                                  float* __restrict__ fd,
                                  float* __restrict__ out)
{
    const int idx = blockIdx.x * blockDim.x + threadIdx.x;
    if (idx < NB * NV) out[IMG_SZ + idx] = 0.0f;     // zero visibility region
    if (idx >= NB * NF) return;
    const int b = idx / NF;
    const int* fp = faces + (size_t)idx * 3;
    const int i0 = fp[0], i1 = fp[1], i2 = fp[2];
    const float* vb = verts + (size_t)b * NV * 3;
    // fixed = vertices * [-1,-1,1]  (exact sign flip)
    const float v0x = -vb[i0*3+0], v0y = -vb[i0*3+1], z0 = vb[i0*3+2];
    const float v1x = -vb[i1*3+0], v1y = -vb[i1*3+1], z1 = vb[i1*3+2];
    const float v2x = -vb[i2*3+0], v2y = -vb[i2*3+1], z2 = vb[i2*3+2];
    const float e01x = __fsub_rn(v1x, v0x), e01y = __fsub_rn(v1y, v0y);
    const float e12x = __fsub_rn(v2x, v1x), e12y = __fsub_rn(v2y, v1y);
    const float e20x = __fsub_rn(v0x, v2x), e20y = __fsub_rn(v0y, v2y);
    // area = cross2(v1-v0, v2-v0), unfused like numpy
    const float area = __fsub_rn(__fmul_rn(e01x, __fsub_rn(v2y, v0y)),
                                 __fmul_rn(e01y, __fsub_rn(v2x, v0x)));
    const bool good = fabsf(area) > 1e-10f;
    const float area_safe = good ? area : 1.0f;
    const float inv_area = good ? __fdiv_rn(1.0f, area) : 0.0f;  // 0 => face never valid
    const float L01 = fmaxf(__fadd_rn(__fmul_rn(e01x,e01x), __fmul_rn(e01y,e01y)), 1e-12f);
    const float L12 = fmaxf(__fadd_rn(__fmul_rn(e12x,e12x), __fmul_rn(e12y,e12y)), 1e-12f);
    const float L20 = fmaxf(__fadd_rn(__fmul_rn(e20x,e20x), __fmul_rn(e20y,e20y)), 1e-12f);
    float* q = fd + (size_t)idx * FST;
    q[0]=v0x;  q[1]=v0y;  q[2]=v1x;  q[3]=v1y;
    q[4]=v2x;  q[5]=v2y;  q[6]=e01x; q[7]=e01y;
    q[8]=e12x; q[9]=e12y; q[10]=e20x; q[11]=e20y;
    q[12]=z0;  q[13]=z1;  q[14]=z2;  q[15]=inv_area;
    q[16]=area_safe; q[17]=L01; q[18]=L12; q[19]=L20;
    q[20]=__fdiv_rn(1.0f, L01); q[21]=__fdiv_rn(1.0f, L12); q[22]=__fdiv_rn(1.0f, L20);
    q[23]=0.0f;
}

__global__ __launch_bounds__(64) void raster_kernel(const float* __restrict__ fd,
                                                    const int* __restrict__ faces,
                                                    float* __restrict__ out)
{
    const int b = blockIdx.z;
    const int x = (blockIdx.x << 3) + (threadIdx.x & 7);
    const int y = (blockIdx.y << 3) + (threadIdx.x >> 3);
    // coords[i] = 1 - (2i+1)/S, exact numpy rounding
    const float px = __fsub_rn(1.0f, __fdiv_rn(__fadd_rn(__fmul_rn(2.0f, (float)x), 1.0f), (float)SDIM));
    const float py = __fsub_rn(1.0f, __fdiv_rn(__fadd_rn(__fmul_rn(2.0f, (float)y), 1.0f), (float)SDIM));

    float tz[KTOP], ts[KTOP];
#pragma unroll
    for (int j = 0; j < KTOP; ++j) { tz[j] = 3e38f; ts[j] = 3e38f; }
    float bestZ = 3e38f;
    int bestIdx = -1;

    const float* __restrict__ fb = fd + (size_t)b * NF * FST;
    for (int f = 0; f < NF; ++f) {
        const float* q = fb + f * FST;
        const float v0x = q[0],  v0y = q[1],  v1x = q[2],  v1y = q[3];
        const float v2x = q[4],  v2y = q[5];
        const float e01x = q[6], e01y = q[7], e12x = q[8], e12y = q[9];
        const float e20x = q[10], e20y = q[11];
        const float z0 = q[12], z1 = q[13], z2 = q[14], inv_area = q[15];

        // exact unfused edge functions (match numpy op-for-op)
        const float c0 = __fsub_rn(__fmul_rn(e12x, __fsub_rn(py, v1y)),
                                   __fmul_rn(e12y, __fsub_rn(px, v1x)));
        const float c1 = __fsub_rn(__fmul_rn(e20x, __fsub_rn(py, v2y)),
                                   __fmul_rn(e20y, __fsub_rn(px, v2x)));
        const float c2 = __fsub_rn(__fmul_rn(e01x, __fsub_rn(py, v0y)),
                                   __fmul_rn(e01y, __fsub_rn(px, v0x)));

        // fast approximate z with rigorous per-face margin
        const float zt = (c0 * z0 + c1 * z1 + c2 * z2) * inv_area;
        const float mg = (fabsf(c0) + fabsf(c1) + fabsf(c2)) * fabsf(inv_area) * 1.5e-6f;
        if (!(zt > -mg)) continue;                 // certainly z<=0 (also kills degenerate faces)
        if (!(zt < tz[KTOP-1] + mg)) continue;     // certainly not in current top-K

        // sign-exact approximate barycentrics (sign(c*inv_area) == sign(c/area))
        const float w0a = c0 * inv_area, w1a = c1 * inv_area, w2a = c2 * inv_area;
        const bool insideA = (w0a > 0.0f) & (w1a > 0.0f) & (w2a > 0.0f);
        const float il01 = q[20], il12 = q[21], il20 = q[22];
        if (!insideA) {
            // conservative reject: real d2 >= line_dist^2 on any violated edge
            float r = 0.0f;
            if (!(w0a > 0.0f)) r = fmaxf(r, c0 * c0 * il12);
            if (!(w1a > 0.0f)) r = fmaxf(r, c1 * c1 * il20);
            if (!(w2a > 0.0f)) r = fmaxf(r, c2 * c2 * il01);
            if (r > BLUR * 1.0001f) continue;
        }

        // ---- exact path (rare): numpy-bit-exact z and validity ----
        const float area = q[16];
        const float w0 = __fdiv_rn(c0, area);
        const float w1 = __fdiv_rn(c1, area);
        const float w2 = __fdiv_rn(c2, area);
        const float z = __fadd_rn(__fadd_rn(__fmul_rn(w0, z0), __fmul_rn(w1, z1)),
                                  __fmul_rn(w2, z2));
        if (!(z > 0.0f)) continue;
        if (!(z < tz[KTOP-1])) continue;           // exact streaming top-k gate

        const bool inside = (w0 > 0.0f) & (w1 > 0.0f) & (w2 > 0.0f);
        float sd;
        if (inside) {
            // inside is always valid (sd=-d2 <= 0 <= BLUR); d2 only feeds prob
            const float mld = fminf(fminf(c0*c0*il12, c1*c1*il20), c2*c2*il01);
            if (mld >= 1e-3f) {
                sd = -1.0f;                         // prob = 1 within 5e-5 of ref
            } else {
                const float L01 = q[17], L12 = q[18], L20 = q[19];
                const float d2 = fminf(fminf(
                    seg_d2_exact(v0x, v0y, e01x, e01y, L01, px, py),
                    seg_d2_exact(v1x, v1y, e12x, e12y, L12, px, py)),
                    seg_d2_exact(v2x, v2y, e20x, e20y, L20, px, py));
                sd = -d2;
            }
        } else {
            const float L01 = q[17], L12 = q[18], L20 = q[19];
            const float d2 = fminf(fminf(
                seg_d2_exact(v0x, v0y, e01x, e01y, L01, px, py),
                seg_d2_exact(v1x, v1y, e12x, e12y, L12, px, py)),
                seg_d2_exact(v2x, v2y, e20x, e20y, L20, px, py));
            if (!(d2 <= BLUR)) continue;            // exact ref validity boundary
            sd = d2;
        }

        if (z < bestZ) { bestZ = z; bestIdx = f; }  // argmin-z, ties -> first index

        // sorted insert into top-K (ascending z; ties keep earlier index first)
        float cz = z, cs = sd;
#pragma unroll
        for (int j = 0; j < KTOP; ++j) {
            if (cz < tz[j]) {
                const float oz = tz[j], os = ts[j];
                tz[j] = cz; ts[j] = cs; cz = oz; cs = os;
            }
        }
    }

    // alpha = 1 - prod_j (1 - sigmoid(-sd_j/SIGMA)) ; empty slots (ts=3e38) give factor 1
    float qq = 1.0f;
#pragma unroll
    for (int j = 0; j < KTOP; ++j)
        qq *= 1.0f / (1.0f + __expf(-ts[j] * 1e4f));
    const float alpha = 1.0f - qq;
    out[(size_t)b * (SDIM * SDIM) + y * SDIM + x] = alpha;

    if (bestIdx >= 0) {
        const int* fp = faces + ((size_t)b * NF + bestIdx) * 3;
        float* vis = out + IMG_SZ;
        vis[b * NV + fp[0]] = 1.0f;
        vis[b * NV + fp[1]] = 1.0f;
        vis[b * NV + fp[2]] = 1.0f;
    }
}

extern "C" void kernel_launch(void* const* d_in, const int* in_sizes, int n_in,
                              void* d_out, int out_size, void* d_ws, size_t ws_size,
                              hipStream_t stream)
{
    const float* verts = (const float*)d_in[0];
    const int*   faces = (const int*)d_in[1];
    float* out = (float*)d_out;
    float* fd  = (float*)d_ws;   // NB*NF*FST*4 = 960 KB scratch

    const int total = NB * NV;   // 10046 >= NB*NF, covers both vis-zero and faces
    preprocess_kernel<<<dim3((total + 255) / 256), dim3(256), 0, stream>>>(verts, faces, fd, out);
    raster_kernel<<<dim3(SDIM / 8, SDIM / 8, NB), dim3(64), 0, stream>>>(fd, faces, out);
}

// Round 2
// 1256.736 us; speedup vs baseline: 1.3053x; 1.3053x over previous
//
#include <hip/hip_runtime.h>
#include <math.h>

#define SDIM 224
#define KTOP 10
#define NB 2
#define NV 5023
#define NF 5000
#define FST 24          // floats per preprocessed face struct
#define BLUR 1e-4f
#define IMG_SZ (NB * SDIM * SDIM)   // 100352
#define NW 8            // waves (face segments) per block
#define SEG ((NF + NW - 1) / NW)    // 625

// Exact (numpy-op-order) point-segment distance^2, matching _edge_d2:
// t = clip(dot(ap,ab)/max(dot(ab,ab),1e-12), 0, 1); proj = a + t*ab; |p-proj|^2
__device__ __forceinline__ float seg_d2_exact(float ax, float ay, float abx, float aby,
                                              float L, float px, float py) {
    float apx = __fsub_rn(px, ax), apy = __fsub_rn(py, ay);
    float dot = __fadd_rn(__fmul_rn(apx, abx), __fmul_rn(apy, aby));
    float t = __fdiv_rn(dot, L);
    t = fminf(fmaxf(t, 0.0f), 1.0f);
    float prx = __fadd_rn(ax, __fmul_rn(t, abx));
    float pry = __fadd_rn(ay, __fmul_rn(t, aby));
    float dx = __fsub_rn(px, prx), dy = __fsub_rn(py, pry);
    return __fadd_rn(__fmul_rn(dx, dx), __fmul_rn(dy, dy));
}

__global__ void preprocess_kernel(const float* __restrict__ verts,
                                  const int* __restrict__ faces,
                                  float* __restrict__ fd,
                                  float* __restrict__ out)
{
    const int idx = blockIdx.x * blockDim.x + threadIdx.x;
    if (idx < NB * NV) out[IMG_SZ + idx] = 0.0f;     // zero visibility region
    if (idx >= NB * NF) return;
    const int b = idx / NF;
    const int* fp = faces + (size_t)idx * 3;
    const int i0 = fp[0], i1 = fp[1], i2 = fp[2];
    const float* vb = verts + (size_t)b * NV * 3;
    // fixed = vertices * [-1,-1,1]  (exact sign flip)
    const float v0x = -vb[i0*3+0], v0y = -vb[i0*3+1], z0 = vb[i0*3+2];
    const float v1x = -vb[i1*3+0], v1y = -vb[i1*3+1], z1 = vb[i1*3+2];
    const float v2x = -vb[i2*3+0], v2y = -vb[i2*3+1], z2 = vb[i2*3+2];
    const float e01x = __fsub_rn(v1x, v0x), e01y = __fsub_rn(v1y, v0y);
    const float e12x = __fsub_rn(v2x, v1x), e12y = __fsub_rn(v2y, v1y);
    const float e20x = __fsub_rn(v0x, v2x), e20y = __fsub_rn(v0y, v2y);
    // area = cross2(v1-v0, v2-v0), unfused like numpy
    const float area = __fsub_rn(__fmul_rn(e01x, __fsub_rn(v2y, v0y)),
                                 __fmul_rn(e01y, __fsub_rn(v2x, v0x)));
    const bool good = fabsf(area) > 1e-10f;
    const float area_safe = good ? area : 1.0f;
    const float inv_area = good ? __fdiv_rn(1.0f, area) : 0.0f;  // 0 => face never valid
    const float L01 = fmaxf(__fadd_rn(__fmul_rn(e01x,e01x), __fmul_rn(e01y,e01y)), 1e-12f);
    const float L12 = fmaxf(__fadd_rn(__fmul_rn(e12x,e12x), __fmul_rn(e12y,e12y)), 1e-12f);
    const float L20 = fmaxf(__fadd_rn(__fmul_rn(e20x,e20x), __fmul_rn(e20y,e20y)), 1e-12f);
    float* q = fd + (size_t)idx * FST;
    q[0]=v0x;  q[1]=v0y;  q[2]=v1x;  q[3]=v1y;
    q[4]=v2x;  q[5]=v2y;  q[6]=e01x; q[7]=e01y;
    q[8]=e12x; q[9]=e12y; q[10]=e20x; q[11]=e20y;
    q[12]=z0;  q[13]=z1;  q[14]=z2;  q[15]=inv_area;
    q[16]=area_safe; q[17]=L01; q[18]=L12; q[19]=L20;
    q[20]=__fdiv_rn(1.0f, L01); q[21]=__fdiv_rn(1.0f, L12); q[22]=__fdiv_rn(1.0f, L20);
    q[23]=0.0f;
}

__global__ __launch_bounds__(64 * NW) void raster_kernel(const float* __restrict__ fd,
                                                         const int* __restrict__ faces,
                                                         float* __restrict__ out)
{
    const int b = blockIdx.z;
    const int lane = threadIdx.x & 63;
    const int w = threadIdx.x >> 6;          // face segment for this wave
    const int x = (blockIdx.x << 3) + (lane & 7);
    const int y = (blockIdx.y << 3) + (lane >> 3);
    // coords[i] = 1 - (2i+1)/S, exact numpy rounding
    const float px = __fsub_rn(1.0f, __fdiv_rn(__fadd_rn(__fmul_rn(2.0f, (float)x), 1.0f), (float)SDIM));
    const float py = __fsub_rn(1.0f, __fdiv_rn(__fadd_rn(__fmul_rn(2.0f, (float)y), 1.0f), (float)SDIM));

    float tz[KTOP], ts[KTOP];
#pragma unroll
    for (int j = 0; j < KTOP; ++j) { tz[j] = 3e38f; ts[j] = 3e38f; }
    float bestZ = 3e38f;
    int bestIdx = -1;

    const float* __restrict__ fb = fd + (size_t)b * NF * FST;
    const int fEnd = min(NF, (w + 1) * SEG);
    for (int f = w * SEG; f < fEnd; ++f) {
        const float* q = fb + f * FST;
        const float v0x = q[0],  v0y = q[1],  v1x = q[2],  v1y = q[3];
        const float v2x = q[4],  v2y = q[5];
        const float e01x = q[6], e01y = q[7], e12x = q[8], e12y = q[9];
        const float e20x = q[10], e20y = q[11];
        const float z0 = q[12], z1 = q[13], z2 = q[14], inv_area = q[15];

        // exact unfused edge functions (match numpy op-for-op)
        const float c0 = __fsub_rn(__fmul_rn(e12x, __fsub_rn(py, v1y)),
                                   __fmul_rn(e12y, __fsub_rn(px, v1x)));
        const float c1 = __fsub_rn(__fmul_rn(e20x, __fsub_rn(py, v2y)),
                                   __fmul_rn(e20y, __fsub_rn(px, v2x)));
        const float c2 = __fsub_rn(__fmul_rn(e01x, __fsub_rn(py, v0y)),
                                   __fmul_rn(e01y, __fsub_rn(px, v0x)));

        // fast approximate z with rigorous per-face margin
        const float zt = (c0 * z0 + c1 * z1 + c2 * z2) * inv_area;
        const float mg = (fabsf(c0) + fabsf(c1) + fabsf(c2)) * fabsf(inv_area) * 1.5e-6f;
        if (!(zt > -mg)) continue;                 // certainly z<=0 (also kills degenerate faces)
        if (!(zt < tz[KTOP-1] + mg)) continue;     // certainly not in current top-K

        // sign-exact approximate barycentrics (sign(c*inv_area) == sign(c/area))
        const float w0a = c0 * inv_area, w1a = c1 * inv_area, w2a = c2 * inv_area;
        const bool insideA = (w0a > 0.0f) & (w1a > 0.0f) & (w2a > 0.0f);
        const float il01 = q[20], il12 = q[21], il20 = q[22];
        if (!insideA) {
            // conservative reject: real d2 >= line_dist^2 on any violated edge
            float r = 0.0f;
            if (!(w0a > 0.0f)) r = fmaxf(r, c0 * c0 * il12);
            if (!(w1a > 0.0f)) r = fmaxf(r, c1 * c1 * il20);
            if (!(w2a > 0.0f)) r = fmaxf(r, c2 * c2 * il01);
            if (r > BLUR * 1.0001f) continue;
        }

        // ---- exact path (rare): numpy-bit-exact z and validity ----
        const float area = q[16];
        const float w0 = __fdiv_rn(c0, area);
        const float w1 = __fdiv_rn(c1, area);
        const float w2 = __fdiv_rn(c2, area);
        const float z = __fadd_rn(__fadd_rn(__fmul_rn(w0, z0), __fmul_rn(w1, z1)),
                                  __fmul_rn(w2, z2));
        if (!(z > 0.0f)) continue;
        if (!(z < tz[KTOP-1])) continue;           // exact streaming top-k gate

        const bool inside = (w0 > 0.0f) & (w1 > 0.0f) & (w2 > 0.0f);
        float sd;
        if (inside) {
            // inside is always valid (sd=-d2 <= 0 <= BLUR); d2 only feeds prob
            const float mld = fminf(fminf(c0*c0*il12, c1*c1*il20), c2*c2*il01);
            if (mld >= 1e-3f) {
                sd = -1.0f;                         // prob = 1 within 5e-5 of ref
            } else {
                const float L01 = q[17], L12 = q[18], L20 = q[19];
                const float d2 = fminf(fminf(
                    seg_d2_exact(v0x, v0y, e01x, e01y, L01, px, py),
                    seg_d2_exact(v1x, v1y, e12x, e12y, L12, px, py)),
                    seg_d2_exact(v2x, v2y, e20x, e20y, L20, px, py));
                sd = -d2;
            }
        } else {
            const float L01 = q[17], L12 = q[18], L20 = q[19];
            const float d2 = fminf(fminf(
                seg_d2_exact(v0x, v0y, e01x, e01y, L01, px, py),
                seg_d2_exact(v1x, v1y, e12x, e12y, L12, px, py)),
                seg_d2_exact(v2x, v2y, e20x, e20y, L20, px, py));
            if (!(d2 <= BLUR)) continue;            // exact ref validity boundary
            sd = d2;
        }

        if (z < bestZ) { bestZ = z; bestIdx = f; }  // argmin-z, ties -> first index

        // sorted insert into top-K (ascending z; ties keep earlier index first)
        float cz = z, cs = sd;
#pragma unroll
        for (int j = 0; j < KTOP; ++j) {
            if (cz < tz[j]) {
                const float oz = tz[j], os = ts[j];
                tz[j] = cz; ts[j] = cs; cz = oz; cs = os;
            }
        }
    }

    // ---- merge NW per-wave sorted top-K lists per pixel via LDS ----
    // stride 11 floats: lanes hit banks (11*lane)%32, gcd(11,32)=1 -> 2-way only (free)
    __shared__ float sZ[NW][64][11];
    __shared__ float sS[NW][64][11];
    __shared__ float sBZ[NW][64];
    __shared__ int   sBI[NW][64];
#pragma unroll
    for (int j = 0; j < KTOP; ++j) { sZ[w][lane][j] = tz[j]; sS[w][lane][j] = ts[j]; }
    sZ[w][lane][KTOP] = 3e38f;      // sentinel for exhausted-list reads (pad slot)
    sBZ[w][lane] = bestZ;
    sBI[w][lane] = bestIdx;
    __syncthreads();

    if (threadIdx.x < 64) {
        const int p = threadIdx.x;
        // merge argmin: strict < + ascending segment scan = lowest face index on ties
        float bz = sBZ[0][p]; int bi = sBI[0][p];
#pragma unroll
        for (int w2 = 1; w2 < NW; ++w2) {
            if (sBZ[w2][p] < bz) { bz = sBZ[w2][p]; bi = sBI[w2][p]; }
        }
        // 8-way sorted-list merge, take K smallest z (ties -> lowest segment/index),
        // multiply factors in ascending-z order (identical order to the reference)
        int ptr[NW];
#pragma unroll
        for (int w2 = 0; w2 < NW; ++w2) ptr[w2] = 0;
        float prod = 1.0f;
#pragma unroll
        for (int k = 0; k < KTOP; ++k) {
            float mz = 3e38f; int mw = -1;
#pragma unroll
            for (int w2 = 0; w2 < NW; ++w2) {
                const float zc = sZ[w2][p][ptr[w2]];
                if (zc < mz) { mz = zc; mw = w2; }
            }
            float sd = 3e38f;
#pragma unroll
            for (int w2 = 0; w2 < NW; ++w2) {
                if (w2 == mw) { sd = sS[w2][p][ptr[w2]]; ptr[w2]++; }
            }
            prod *= 1.0f / (1.0f + __expf(-sd * 1e4f));   // empty slot: factor = 1
        }
        const float alpha = 1.0f - prod;
        const int xx = p & 7, yy = p >> 3;
        const int gx = (blockIdx.x << 3) + xx;
        const int gy = (blockIdx.y << 3) + yy;
        out[(size_t)b * (SDIM * SDIM) + gy * SDIM + gx] = alpha;

        if (bi >= 0) {
            const int* fp = faces + ((size_t)b * NF + bi) * 3;
            float* vis = out + IMG_SZ;
            vis[b * NV + fp[0]] = 1.0f;
            vis[b * NV + fp[1]] = 1.0f;
            vis[b * NV + fp[2]] = 1.0f;
        }
    }
}

extern "C" void kernel_launch(void* const* d_in, const int* in_sizes, int n_in,
                              void* d_out, int out_size, void* d_ws, size_t ws_size,
                              hipStream_t stream)
{
    const float* verts = (const float*)d_in[0];
    const int*   faces = (const int*)d_in[1];
    float* out = (float*)d_out;
    float* fd  = (float*)d_ws;   // NB*NF*FST*4 = 960 KB scratch

    const int total = NB * NV;   // 10046 >= NB*NF, covers both vis-zero and faces
    preprocess_kernel<<<dim3((total + 255) / 256), dim3(256), 0, stream>>>(verts, faces, fd, out);
    raster_kernel<<<dim3(SDIM / 8, SDIM / 8, NB), dim3(64 * NW), 0, stream>>>(fd, faces, out);
}

// Round 4
// 651.134 us; speedup vs baseline: 2.5194x; 1.9301x over previous
//
#include <hip/hip_runtime.h>
#include <math.h>

#define SDIM 224
#define KTOP 10
#define NB 2
#define NV 5023
#define NF 5000
#define FSTB 24          // floats per heavy face struct
#define BLUR 1e-4f
#define IMG_SZ (NB * SDIM * SDIM)   // 100352
#define NW 8             // face segments (waves) per block
#define SEG (NF / NW)    // 625

// Exact (numpy-op-order) point-segment distance^2, matching _edge_d2.
__device__ __forceinline__ float seg_d2_exact(float ax, float ay, float abx, float aby,
                                              float L, float px, float py) {
    float apx = __fsub_rn(px, ax), apy = __fsub_rn(py, ay);
    float dot = __fadd_rn(__fmul_rn(apx, abx), __fmul_rn(apy, aby));
    float t = __fdiv_rn(dot, L);
    t = fminf(fmaxf(t, 0.0f), 1.0f);
    float prx = __fadd_rn(ax, __fmul_rn(t, abx));
    float pry = __fadd_rn(ay, __fmul_rn(t, aby));
    float dx = __fsub_rn(px, prx), dy = __fsub_rn(py, pry);
    return __fadd_rn(__fmul_rn(dx, dx), __fmul_rn(dy, dy));
}

// fdA[2f]   = {Zx, Zy, Zc, mgc}: affine z(px,py) + conservative |zt - z_numpy| bound
// fdA[2f+1] = {cx, cy, RR, 0}:  bounding circle (centroid, (maxdist+0.0111)^2*1.0001)
// fdB[f*24]: exact-float face struct for the heavy path.
__global__ void preprocess_kernel(const float* __restrict__ verts,
                                  const int* __restrict__ faces,
                                  float4* __restrict__ fdA,
                                  float* __restrict__ fdB,
                                  float* __restrict__ out)
{
    const int idx = blockIdx.x * blockDim.x + threadIdx.x;
    if (idx < NB * NV) out[IMG_SZ + idx] = 0.0f;     // zero visibility region
    if (idx >= NB * NF) return;
    const int b = idx / NF;
    const int* fp = faces + (size_t)idx * 3;
    const int i0 = fp[0], i1 = fp[1], i2 = fp[2];
    const float* vb = verts + (size_t)b * NV * 3;
    const float v0x = -vb[i0*3+0], v0y = -vb[i0*3+1], z0 = vb[i0*3+2];
    const float v1x = -vb[i1*3+0], v1y = -vb[i1*3+1], z1 = vb[i1*3+2];
    const float v2x = -vb[i2*3+0], v2y = -vb[i2*3+1], z2 = vb[i2*3+2];
    const float e01x = __fsub_rn(v1x, v0x), e01y = __fsub_rn(v1y, v0y);
    const float e12x = __fsub_rn(v2x, v1x), e12y = __fsub_rn(v2y, v1y);
    const float e20x = __fsub_rn(v0x, v2x), e20y = __fsub_rn(v0y, v2y);
    const float area = __fsub_rn(__fmul_rn(e01x, __fsub_rn(v2y, v0y)),
                                 __fmul_rn(e01y, __fsub_rn(v2x, v0x)));
    const bool good = fabsf(area) > 1e-10f;
    const float area_safe = good ? area : 1.0f;
    const float L01 = fmaxf(__fadd_rn(__fmul_rn(e01x,e01x), __fmul_rn(e01y,e01y)), 1e-12f);
    const float L12 = fmaxf(__fadd_rn(__fmul_rn(e12x,e12x), __fmul_rn(e12y,e12y)), 1e-12f);
    const float L20 = fmaxf(__fadd_rn(__fmul_rn(e20x,e20x), __fmul_rn(e20y,e20y)), 1e-12f);

    double Zx = 0.0, Zy = 0.0, Zc = 0.0;
    float mgc = 0.0f, ccx = 0.0f, ccy = 0.0f, RR = -1.0f;   // RR=-1 => always reject
    if (good) {
        const double invA = 1.0 / (double)area;
        const double c0c = (double)e12y*v1x - (double)e12x*v1y;
        const double c1c = (double)e20y*v2x - (double)e20x*v2y;
        const double c2c = (double)e01y*v0x - (double)e01x*v0y;
        Zx = (-(double)e12y*z0 - (double)e20y*z1 - (double)e01y*z2) * invA;
        Zy = ( (double)e12x*z0 + (double)e20x*z1 + (double)e01x*z2) * invA;
        Zc = (c0c*z0 + c1c*z1 + c2c*z2) * invA;
        // magnitude bound of all intermediates in numpy's z and the affine eval
        const double B0 = fabs((double)e12x)*(1.0+fabs((double)v1y)) + fabs((double)e12y)*(1.0+fabs((double)v1x));
        const double B1 = fabs((double)e20x)*(1.0+fabs((double)v2y)) + fabs((double)e20y)*(1.0+fabs((double)v2x));
        const double B2 = fabs((double)e01x)*(1.0+fabs((double)v0y)) + fabs((double)e01y)*(1.0+fabs((double)v0x));
        const double B = (B0*(double)z0 + B1*(double)z1 + B2*(double)z2) * fabs(invA);
        mgc = (float)(2.5e-6 * B) + 1e-20f;   // ~2.8x over worst-case combined rounding error
        // bounding circle: triangle+blur(0.01) zone is inside disk(centroid, maxdist+0.0111)
        const double cx = ((double)v0x + (double)v1x + (double)v2x) / 3.0;
        const double cy = ((double)v0y + (double)v1y + (double)v2y) / 3.0;
        const double d0 = (v0x-cx)*(v0x-cx) + (v0y-cy)*(v0y-cy);
        const double d1 = (v1x-cx)*(v1x-cx) + (v1y-cy)*(v1y-cy);
        const double d2 = (v2x-cx)*(v2x-cx) + (v2y-cy)*(v2y-cy);
        const double R = sqrt(fmax(d0, fmax(d1, d2))) + 0.0111;
        ccx = (float)cx; ccy = (float)cy;
        RR = (float)(R * R) * 1.0001f;
    }
    fdA[2*idx]   = make_float4((float)Zx, (float)Zy, (float)Zc, mgc);
    fdA[2*idx+1] = make_float4(ccx, ccy, RR, 0.0f);
    float* q = fdB + (size_t)idx * FSTB;
    q[0]=v0x;  q[1]=v0y;  q[2]=v1x;  q[3]=v1y;  q[4]=v2x;  q[5]=v2y;
    q[6]=e01x; q[7]=e01y; q[8]=e12x; q[9]=e12y; q[10]=e20x; q[11]=e20y;
    q[12]=z0;  q[13]=z1;  q[14]=z2;  q[15]=area_safe;
    q[16]=L01; q[17]=L12; q[18]=L20;
    q[19]=__fdiv_rn(1.0f, L01); q[20]=__fdiv_rn(1.0f, L12); q[21]=__fdiv_rn(1.0f, L20);
    q[22]=0.0f; q[23]=0.0f;
}

__global__ __launch_bounds__(64 * NW) void raster_kernel(const float4* __restrict__ fdA,
                                                         const float* __restrict__ fdB,
                                                         const int* __restrict__ faces,
                                                         float* __restrict__ out)
{
    const int b = blockIdx.z;
    const int lane = threadIdx.x & 63;
    // readfirstlane => compiler-provable wave-uniform segment => scalar face loads
    const int w = __builtin_amdgcn_readfirstlane((int)(threadIdx.x >> 6));
    const int x = (blockIdx.x << 3) + (lane & 7);
    const int y = (blockIdx.y << 3) + (lane >> 3);
    const float px = __fsub_rn(1.0f, __fdiv_rn(__fadd_rn(__fmul_rn(2.0f, (float)x), 1.0f), (float)SDIM));
    const float py = __fsub_rn(1.0f, __fdiv_rn(__fadd_rn(__fmul_rn(2.0f, (float)y), 1.0f), (float)SDIM));

    float tz[KTOP], ts[KTOP];
#pragma unroll
    for (int j = 0; j < KTOP; ++j) { tz[j] = 3e38f; ts[j] = 3e38f; }
    float bestZ = 3e38f;
    int bestIdx = -1;

    const float4* __restrict__ fa = fdA + (size_t)b * NF * 2;
    const float*  __restrict__ fb = fdB + (size_t)b * NF * FSTB;
    const int f0 = w * SEG, f1 = f0 + SEG;
    for (int f = f0; f < f1; ++f) {
        const float4 aA = fa[2*f];
        const float4 aB = fa[2*f+1];
        const float zt  = fmaf(aA.x, px, fmaf(aA.y, py, aA.z));
        const float dcx = px - aB.x, dcy = py - aB.y;
        const float d2c = fmaf(dcx, dcx, dcy*dcy);
        const float thr = tz[KTOP-1];
        const bool pass = (d2c <= aB.z) & (zt > -aA.w) & (zt < thr + aA.w);
        if (!__any(pass)) continue;

        // wave-uniform scalar loads of the heavy struct
        const float* q = fb + (size_t)f * FSTB;
        const float v0x=q[0], v0y=q[1], v1x=q[2], v1y=q[3], v2x=q[4], v2y=q[5];
        const float e01x=q[6], e01y=q[7], e12x=q[8], e12y=q[9], e20x=q[10], e20y=q[11];
        const float z0=q[12], z1=q[13], z2=q[14], area=q[15];
        const float L01=q[16], L12=q[17], L20=q[18];
        const float il01=q[19], il12=q[20], il20=q[21];
        if (!pass) continue;

        // exact unfused edge functions (match numpy op-for-op)
        const float c0 = __fsub_rn(__fmul_rn(e12x, __fsub_rn(py, v1y)),
                                   __fmul_rn(e12y, __fsub_rn(px, v1x)));
        const float c1 = __fsub_rn(__fmul_rn(e20x, __fsub_rn(py, v2y)),
                                   __fmul_rn(e20y, __fsub_rn(px, v2x)));
        const float c2 = __fsub_rn(__fmul_rn(e01x, __fsub_rn(py, v0y)),
                                   __fmul_rn(e01y, __fsub_rn(px, v0x)));

        // sign-exact pre-inside test; outcome-equivalent to sign(c/area)
        const bool ap = area > 0.0f;
        const bool s0 = ap ? (c0 > 0.0f) : (c0 < 0.0f);
        const bool s1 = ap ? (c1 > 0.0f) : (c1 < 0.0f);
        const bool s2 = ap ? (c2 > 0.0f) : (c2 < 0.0f);
        if (!(s0 & s1 & s2)) {
            // conservative reject: real d2 >= line_dist^2 on any violated edge
            float r = 0.0f;
            if (!s0) r = fmaxf(r, c0 * c0 * il12);
            if (!s1) r = fmaxf(r, c1 * c1 * il20);
            if (!s2) r = fmaxf(r, c2 * c2 * il01);
            if (r > BLUR * 1.0001f) continue;
        }

        // ---- exact path: numpy-bit-exact z and validity ----
        const float w0 = __fdiv_rn(c0, area);
        const float w1 = __fdiv_rn(c1, area);
        const float w2 = __fdiv_rn(c2, area);
        const float z = __fadd_rn(__fadd_rn(__fmul_rn(w0, z0), __fmul_rn(w1, z1)),
                                  __fmul_rn(w2, z2));
        if (!(z > 0.0f)) continue;
        if (!(z < tz[KTOP-1])) continue;           // exact streaming top-k gate

        const bool inside = (w0 > 0.0f) & (w1 > 0.0f) & (w2 > 0.0f);
        float sd;
        if (inside) {
            // inside is always valid; d2 only feeds prob
            const float mld = fminf(fminf(c0*c0*il12, c1*c1*il20), c2*c2*il01);
            if (mld >= 1e-3f) {
                sd = -1.0f;                         // sigmoid saturated: alpha err < 5e-5
            } else {
                const float d2 = fminf(fminf(
                    seg_d2_exact(v0x, v0y, e01x, e01y, L01, px, py),
                    seg_d2_exact(v1x, v1y, e12x, e12y, L12, px, py)),
                    seg_d2_exact(v2x, v2y, e20x, e20y, L20, px, py));
                sd = -d2;
            }
        } else {
            const float d2 = fminf(fminf(
                seg_d2_exact(v0x, v0y, e01x, e01y, L01, px, py),
                seg_d2_exact(v1x, v1y, e12x, e12y, L12, px, py)),
                seg_d2_exact(v2x, v2y, e20x, e20y, L20, px, py));
            if (!(d2 <= BLUR)) continue;            // exact ref validity boundary
            sd = d2;
        }

        if (z < bestZ) { bestZ = z; bestIdx = f; }  // argmin-z, ties -> first index

        // sorted insert into top-K (ascending z; ties keep earlier index first)
        float cz = z, cs = sd;
#pragma unroll
        for (int j = 0; j < KTOP; ++j) {
            if (cz < tz[j]) {
                const float oz = tz[j], os = ts[j];
                tz[j] = cz; ts[j] = cs; cz = oz; cs = os;
            }
        }
    }

    // ---- merge NW per-wave sorted top-K lists per pixel via LDS (R2-proven) ----
    __shared__ float sZ[NW][64][11];
    __shared__ float sS[NW][64][11];
    __shared__ float sBZ[NW][64];
    __shared__ int   sBI[NW][64];
#pragma unroll
    for (int j = 0; j < KTOP; ++j) { sZ[w][lane][j] = tz[j]; sS[w][lane][j] = ts[j]; }
    sZ[w][lane][KTOP] = 3e38f;      // sentinel for exhausted-list reads (pad slot)
    sBZ[w][lane] = bestZ;
    sBI[w][lane] = bestIdx;
    __syncthreads();

    if (threadIdx.x < 64) {
        const int p = threadIdx.x;
        // merge argmin: strict < + ascending segment scan = lowest face index on ties
        float bz = sBZ[0][p]; int bi = sBI[0][p];
#pragma unroll
        for (int w2 = 1; w2 < NW; ++w2) {
            if (sBZ[w2][p] < bz) { bz = sBZ[w2][p]; bi = sBI[w2][p]; }
        }
        // 8-way sorted-list merge, K smallest z (ties -> lowest segment/index),
        // factors multiplied in ascending-z order (identical order to the reference)
        int ptr[NW];
#pragma unroll
        for (int w2 = 0; w2 < NW; ++w2) ptr[w2] = 0;
        float prod = 1.0f;
#pragma unroll
        for (int k = 0; k < KTOP; ++k) {
            float mz = 3e38f; int mw = -1;
#pragma unroll
            for (int w2 = 0; w2 < NW; ++w2) {
                const float zc = sZ[w2][p][ptr[w2]];
                if (zc < mz) { mz = zc; mw = w2; }
            }
            float sd = 3e38f;
#pragma unroll
            for (int w2 = 0; w2 < NW; ++w2) {
                if (w2 == mw) { sd = sS[w2][p][ptr[w2]]; ptr[w2]++; }
            }
            prod *= 1.0f / (1.0f + __expf(-sd * 1e4f));   // empty slot: factor = 1
        }
        const float alpha = 1.0f - prod;
        const int gx = (blockIdx.x << 3) + (p & 7);
        const int gy = (blockIdx.y << 3) + (p >> 3);
        out[(size_t)b * (SDIM * SDIM) + gy * SDIM + gx] = alpha;

        if (bi >= 0) {
            const int* fp = faces + ((size_t)b * NF + bi) * 3;
            float* vis = out + IMG_SZ;
            vis[b * NV + fp[0]] = 1.0f;
            vis[b * NV + fp[1]] = 1.0f;
            vis[b * NV + fp[2]] = 1.0f;
        }
    }
}

extern "C" void kernel_launch(void* const* d_in, const int* in_sizes, int n_in,
                              void* d_out, int out_size, void* d_ws, size_t ws_size,
                              hipStream_t stream)
{
    const float* verts = (const float*)d_in[0];
    const int*   faces = (const int*)d_in[1];
    float* out = (float*)d_out;
    float4* fdA = (float4*)d_ws;                          // NB*NF*32 B = 320 KB
    float*  fdB = (float*)((char*)d_ws + NB * NF * 32);   // NB*NF*96 B = 960 KB

    const int total = NB * NV;   // 10046 >= NB*NF
    preprocess_kernel<<<dim3((total + 255) / 256), dim3(256), 0, stream>>>(verts, faces, fdA, fdB, out);
    raster_kernel<<<dim3(SDIM / 8, SDIM / 8, NB), dim3(64 * NW), 0, stream>>>(fdA, fdB, faces, out);
}

// Round 5
// 189.545 us; speedup vs baseline: 8.6546x; 3.4352x over previous
//
#include <hip/hip_runtime.h>
#include <math.h>

#define SDIM 224
#define KTOP 10
#define NB 2
#define NV 5023
#define NF 5000
#define FSTB 24          // floats per heavy face struct
#define BLUR 1e-4f
#define IMG_SZ (NB * SDIM * SDIM)   // 100352
#define NW 8             // waves per block
#define SEG (NF / NW)    // 625 (fallback segmentation)
#define CAP 1024         // LDS survivor-list capacity
#define HT 0.031251f     // tile half-extent (7/224) + float slop
#define COV_THR 0.04422f // halfdiag(0.044194)+eps: certain whole-tile cover
#define REL_THR (-0.0543f) // -(halfdiag + 0.01 blur reach + eps)

// Exact (numpy-op-order) point-segment distance^2, matching _edge_d2.
__device__ __forceinline__ float seg_d2_exact(float ax, float ay, float abx, float aby,
                                              float L, float px, float py) {
    float apx = __fsub_rn(px, ax), apy = __fsub_rn(py, ay);
    float dot = __fadd_rn(__fmul_rn(apx, abx), __fmul_rn(apy, aby));
    float t = __fdiv_rn(dot, L);
    t = fminf(fmaxf(t, 0.0f), 1.0f);
    float prx = __fadd_rn(ax, __fmul_rn(t, abx));
    float pry = __fadd_rn(ay, __fmul_rn(t, aby));
    float dx = __fsub_rn(px, prx), dy = __fsub_rn(py, pry);
    return __fadd_rn(__fmul_rn(dx, dx), __fmul_rn(dy, dy));
}

// fdA[2f]   = {Zx, Zy, Zc, mgc}: affine z(px,py) + conservative |zt - z_numpy| bound
// fdA[2f+1] = {cx, cy, RR, 0}:  bounding circle for the per-pixel gate
// fdB[f*24]: exact-float face struct for the heavy path
// fdC[3f..]: inward-normalized edge lines {n0x,n0y,n0c,n1x},{n1y,n1c,n2x,n2y},{n2c,0,0,0}
__global__ void preprocess_kernel(const float* __restrict__ verts,
                                  const int* __restrict__ faces,
                                  float4* __restrict__ fdA,
                                  float* __restrict__ fdB,
                                  float4* __restrict__ fdC,
                                  float* __restrict__ out)
{
    const int idx = blockIdx.x * blockDim.x + threadIdx.x;
    if (idx < NB * NV) out[IMG_SZ + idx] = 0.0f;     // zero visibility region
    if (idx >= NB * NF) return;
    const int b = idx / NF;
    const int* fp = faces + (size_t)idx * 3;
    const int i0 = fp[0], i1 = fp[1], i2 = fp[2];
    const float* vb = verts + (size_t)b * NV * 3;
    const float v0x = -vb[i0*3+0], v0y = -vb[i0*3+1], z0 = vb[i0*3+2];
    const float v1x = -vb[i1*3+0], v1y = -vb[i1*3+1], z1 = vb[i1*3+2];
    const float v2x = -vb[i2*3+0], v2y = -vb[i2*3+1], z2 = vb[i2*3+2];
    const float e01x = __fsub_rn(v1x, v0x), e01y = __fsub_rn(v1y, v0y);
    const float e12x = __fsub_rn(v2x, v1x), e12y = __fsub_rn(v2y, v1y);
    const float e20x = __fsub_rn(v0x, v2x), e20y = __fsub_rn(v0y, v2y);
    const float area = __fsub_rn(__fmul_rn(e01x, __fsub_rn(v2y, v0y)),
                                 __fmul_rn(e01y, __fsub_rn(v2x, v0x)));
    const bool good = fabsf(area) > 1e-10f;
    const float area_safe = good ? area : 1.0f;
    const float L01 = fmaxf(__fadd_rn(__fmul_rn(e01x,e01x), __fmul_rn(e01y,e01y)), 1e-12f);
    const float L12 = fmaxf(__fadd_rn(__fmul_rn(e12x,e12x), __fmul_rn(e12y,e12y)), 1e-12f);
    const float L20 = fmaxf(__fadd_rn(__fmul_rn(e20x,e20x), __fmul_rn(e20y,e20y)), 1e-12f);

    double Zx = 0.0, Zy = 0.0, Zc = 0.0;
    float mgc = 0.0f, ccx = 0.0f, ccy = 0.0f, RR = -1.0f;
    float n0x=0,n0y=0,n0c=-3e38f, n1x=0,n1y=0,n1c=-3e38f, n2x=0,n2y=0,n2c=-3e38f;
    if (good) {
        const double invA = 1.0 / (double)area;
        const double c0c = (double)e12y*v1x - (double)e12x*v1y;
        const double c1c = (double)e20y*v2x - (double)e20x*v2y;
        const double c2c = (double)e01y*v0x - (double)e01x*v0y;
        Zx = (-(double)e12y*z0 - (double)e20y*z1 - (double)e01y*z2) * invA;
        Zy = ( (double)e12x*z0 + (double)e20x*z1 + (double)e01x*z2) * invA;
        Zc = (c0c*z0 + c1c*z1 + c2c*z2) * invA;
        const double B0 = fabs((double)e12x)*(1.0+fabs((double)v1y)) + fabs((double)e12y)*(1.0+fabs((double)v1x));
        const double B1 = fabs((double)e20x)*(1.0+fabs((double)v2y)) + fabs((double)e20y)*(1.0+fabs((double)v2x));
        const double B2 = fabs((double)e01x)*(1.0+fabs((double)v0y)) + fabs((double)e01y)*(1.0+fabs((double)v0x));
        const double B = (B0*(double)z0 + B1*(double)z1 + B2*(double)z2) * fabs(invA);
        mgc = (float)(2.5e-6 * B) + 1e-20f;
        const double cx = ((double)v0x + (double)v1x + (double)v2x) / 3.0;
        const double cy = ((double)v0y + (double)v1y + (double)v2y) / 3.0;
        const double d0 = (v0x-cx)*(v0x-cx) + (v0y-cy)*(v0y-cy);
        const double d1 = (v1x-cx)*(v1x-cx) + (v1y-cy)*(v1y-cy);
        const double d2 = (v2x-cx)*(v2x-cx) + (v2y-cy)*(v2y-cy);
        const double R = sqrt(fmax(d0, fmax(d1, d2))) + 0.0111;
        ccx = (float)cx; ccy = (float)cy;
        RR = (float)(R * R) * 1.0001f;
        // inward-normalized edge lines: d_i(p) = c_i(p)*sign(area)/len_i, >0 inside
        const double s = (area > 0.0f) ? 1.0 : -1.0;
        const double l12 = sqrt((double)e12x*e12x + (double)e12y*e12y);
        const double l20 = sqrt((double)e20x*e20x + (double)e20y*e20y);
        const double l01 = sqrt((double)e01x*e01x + (double)e01y*e01y);
        const double i12 = s / fmax(l12, 1e-300);
        const double i20 = s / fmax(l20, 1e-300);
        const double i01 = s / fmax(l01, 1e-300);
        n0x = (float)(-(double)e12y * i12);
        n0y = (float)( (double)e12x * i12);
        n0c = (float)(((double)e12y*v1x - (double)e12x*v1y) * i12);
        n1x = (float)(-(double)e20y * i20);
        n1y = (float)( (double)e20x * i20);
        n1c = (float)(((double)e20y*v2x - (double)e20x*v2y) * i20);
        n2x = (float)(-(double)e01y * i01);
        n2y = (float)( (double)e01x * i01);
        n2c = (float)(((double)e01y*v0x - (double)e01x*v0y) * i01);
    }
    fdA[2*idx]   = make_float4((float)Zx, (float)Zy, (float)Zc, mgc);
    fdA[2*idx+1] = make_float4(ccx, ccy, RR, 0.0f);
    fdC[3*idx+0] = make_float4(n0x, n0y, n0c, n1x);
    fdC[3*idx+1] = make_float4(n1y, n1c, n2x, n2y);
    fdC[3*idx+2] = make_float4(n2c, 0.0f, 0.0f, 0.0f);
    float* q = fdB + (size_t)idx * FSTB;
    q[0]=v0x;  q[1]=v0y;  q[2]=v1x;  q[3]=v1y;  q[4]=v2x;  q[5]=v2y;
    q[6]=e01x; q[7]=e01y; q[8]=e12x; q[9]=e12y; q[10]=e20x; q[11]=e20y;
    q[12]=z0;  q[13]=z1;  q[14]=z2;  q[15]=area_safe;
    q[16]=L01; q[17]=L12; q[18]=L20;
    q[19]=__fdiv_rn(1.0f, L01); q[20]=__fdiv_rn(1.0f, L12); q[21]=__fdiv_rn(1.0f, L20);
    q[22]=0.0f; q[23]=0.0f;
}

__global__ __launch_bounds__(64 * NW) void raster_kernel(const float4* __restrict__ fdA,
                                                         const float* __restrict__ fdB,
                                                         const float4* __restrict__ fdC,
                                                         const int* __restrict__ faces,
                                                         float* __restrict__ out)
{
    const int b = blockIdx.z;
    const int lane = threadIdx.x & 63;
    const int w = __builtin_amdgcn_readfirstlane((int)(threadIdx.x >> 6));
    const int x = (blockIdx.x << 3) + (lane & 7);
    const int y = (blockIdx.y << 3) + (lane >> 3);
    const float px = __fsub_rn(1.0f, __fdiv_rn(__fadd_rn(__fmul_rn(2.0f, (float)x), 1.0f), (float)SDIM));
    const float py = __fsub_rn(1.0f, __fdiv_rn(__fadd_rn(__fmul_rn(2.0f, (float)y), 1.0f), (float)SDIM));
    // tile center
    const float pcx = __fsub_rn(1.0f, __fdiv_rn((float)(16 * blockIdx.x + 8), 224.0f));
    const float pcy = __fsub_rn(1.0f, __fdiv_rn((float)(16 * blockIdx.y + 8), 224.0f));

    __shared__ int   sList[CAP];
    __shared__ int   sHist[64];
    __shared__ int   sCnt[NW];
    __shared__ int   sOff[NW];
    __shared__ int   sLen;
    __shared__ float sT;
    __shared__ float sZ[NW][64][11];
    __shared__ float sS[NW][64][11];
    __shared__ float sBZ[NW][64];
    __shared__ int   sBI[NW][64];

    if (threadIdx.x < 64) sHist[threadIdx.x] = 0;
    __syncthreads();

    const float4* __restrict__ fa = fdA + (size_t)b * NF * 2;
    const float*  __restrict__ fb = fdB + (size_t)b * NF * FSTB;
    const float4* __restrict__ fc = fdC + (size_t)b * NF * 3;

    // ---- Phase 1a: tile-level bounds + histogram of certain-cover z_hi ----
    const int f0 = w * SEG, f1 = f0 + SEG;
    float dm[10], zl[10], zh[10];
#pragma unroll
    for (int it = 0; it < 10; ++it) {
        const int f = f0 + it * 64 + lane;
        dm[it] = -3e38f; zl[it] = 3e38f; zh[it] = -3e38f;
        if (f < f1) {
            const float4 a0 = fa[2*f];
            const float4 cA = fc[3*f+0];
            const float4 cB = fc[3*f+1];
            const float4 cC = fc[3*f+2];
            const float d0 = fmaf(cA.x, pcx, fmaf(cA.y, pcy, cA.z));
            const float d1 = fmaf(cA.w, pcx, fmaf(cB.x, pcy, cB.y));
            const float d2 = fmaf(cB.z, pcx, fmaf(cB.w, pcy, cC.x));
            const float dmin = fminf(d0, fminf(d1, d2));
            const float ztc = fmaf(a0.x, pcx, fmaf(a0.y, pcy, a0.z));
            const float spread = fmaf(fabsf(a0.x), HT, fmaf(fabsf(a0.y), HT, 2.0f * a0.w)) + 1e-6f;
            dm[it] = dmin; zl[it] = ztc - spread; zh[it] = ztc + spread;
            if ((dmin >= COV_THR) && (zl[it] > 0.0f)) {
                int bk = (int)floorf((zh[it] - 0.4f) * 53.333332f);
                bk = max(0, min(63, bk));
                atomicAdd(&sHist[bk], 1);
            }
        }
    }
    __syncthreads();

    // ---- Phase 1b: T_tile = conservative upper bound on every pixel's 10th-z ----
    if (threadIdx.x == 0) {
        int cum = 0; float T = 3e38f;
        for (int k2 = 0; k2 < 64; ++k2) {
            cum += sHist[k2];
            if (cum >= KTOP) { T = (k2 >= 63) ? 3e38f : (0.4f + (float)(k2+1) * 0.01875f + 1e-4f); break; }
        }
        sT = T;
    }
    __syncthreads();
    const float Tt = sT;

    // ---- Phase 1c: count survivors per wave ----
    int svMask = 0, cnt = 0;
#pragma unroll
    for (int it = 0; it < 10; ++it) {
        const bool sv = (dm[it] >= REL_THR) && (zl[it] <= Tt) && (zh[it] > 0.0f);
        if (sv) svMask |= (1 << it);
        cnt += (int)__popcll(__ballot(sv));
    }
    if (lane == 0) sCnt[w] = cnt;
    __syncthreads();
    if (threadIdx.x == 0) {
        int acc = 0;
        for (int w2 = 0; w2 < NW; ++w2) { sOff[w2] = acc; acc += sCnt[w2]; }
        sLen = (acc <= CAP) ? acc : -1;   // -1 => overflow, fallback to full scan
    }
    __syncthreads();
    const int Ltot = sLen;

    // ---- Phase 1d: emit survivor list in ascending face order ----
    if (Ltot >= 0) {
        const unsigned long long below = ((lane == 63) ? ~0ull : ((1ull << (lane + 1)) - 1ull)) >> 1;
        int woff = sOff[w];
#pragma unroll
        for (int it = 0; it < 10; ++it) {
            const bool sv = (svMask >> it) & 1;
            const unsigned long long m = __ballot(sv);
            if (sv) sList[woff + (int)__popcll(m & below)] = f0 + it * 64 + lane;
            woff += (int)__popcll(m);
        }
    }
    __syncthreads();

    // ---- Phase 2: exact per-pixel scan over survivors (R4-identical semantics) ----
    float tz[KTOP], ts[KTOP];
#pragma unroll
    for (int j = 0; j < KTOP; ++j) { tz[j] = 3e38f; ts[j] = 3e38f; }
    float bestZ = 3e38f;
    int bestIdx = -1;

    int jbeg, jend;
    if (Ltot >= 0) {
        const int chunk = (Ltot + NW - 1) / NW;
        jbeg = w * chunk; jend = min(Ltot, jbeg + chunk);
    } else {
        jbeg = f0; jend = f1;
    }
    for (int j = jbeg; j < jend; ++j) {
        const int f = (Ltot >= 0) ? __builtin_amdgcn_readfirstlane(sList[j]) : j;
        const float4 aA = fa[2*f];
        const float4 aB = fa[2*f+1];
        const float zt  = fmaf(aA.x, px, fmaf(aA.y, py, aA.z));
        const float dcx = px - aB.x, dcy = py - aB.y;
        const float d2c = fmaf(dcx, dcx, dcy*dcy);
        const float thr = tz[KTOP-1];
        const bool pass = (d2c <= aB.z) & (zt > -aA.w) & (zt < thr + aA.w);
        if (!__any(pass)) continue;

        const float* q = fb + (size_t)f * FSTB;
        const float v0x=q[0], v0y=q[1], v1x=q[2], v1y=q[3], v2x=q[4], v2y=q[5];
        const float e01x=q[6], e01y=q[7], e12x=q[8], e12y=q[9], e20x=q[10], e20y=q[11];
        const float z0=q[12], z1=q[13], z2=q[14], area=q[15];
        const float L01=q[16], L12=q[17], L20=q[18];
        const float il01=q[19], il12=q[20], il20=q[21];
        if (!pass) continue;

        const float c0 = __fsub_rn(__fmul_rn(e12x, __fsub_rn(py, v1y)),
                                   __fmul_rn(e12y, __fsub_rn(px, v1x)));
        const float c1 = __fsub_rn(__fmul_rn(e20x, __fsub_rn(py, v2y)),
                                   __fmul_rn(e20y, __fsub_rn(px, v2x)));
        const float c2 = __fsub_rn(__fmul_rn(e01x, __fsub_rn(py, v0y)),
                                   __fmul_rn(e01y, __fsub_rn(px, v0x)));

        const bool ap = area > 0.0f;
        const bool s0 = ap ? (c0 > 0.0f) : (c0 < 0.0f);
        const bool s1 = ap ? (c1 > 0.0f) : (c1 < 0.0f);
        const bool s2 = ap ? (c2 > 0.0f) : (c2 < 0.0f);
        if (!(s0 & s1 & s2)) {
            float r = 0.0f;
            if (!s0) r = fmaxf(r, c0 * c0 * il12);
            if (!s1) r = fmaxf(r, c1 * c1 * il20);
            if (!s2) r = fmaxf(r, c2 * c2 * il01);
            if (r > BLUR * 1.0001f) continue;
        }

        const float w0 = __fdiv_rn(c0, area);
        const float w1 = __fdiv_rn(c1, area);
        const float w2 = __fdiv_rn(c2, area);
        const float z = __fadd_rn(__fadd_rn(__fmul_rn(w0, z0), __fmul_rn(w1, z1)),
                                  __fmul_rn(w2, z2));
        if (!(z > 0.0f)) continue;
        if (!(z < tz[KTOP-1])) continue;

        const bool inside = (w0 > 0.0f) & (w1 > 0.0f) & (w2 > 0.0f);
        float sd;
        if (inside) {
            const float mld = fminf(fminf(c0*c0*il12, c1*c1*il20), c2*c2*il01);
            if (mld >= 1e-3f) {
                sd = -1.0f;                         // sigmoid saturated: alpha err < 5e-5
            } else {
                const float d2 = fminf(fminf(
                    seg_d2_exact(v0x, v0y, e01x, e01y, L01, px, py),
                    seg_d2_exact(v1x, v1y, e12x, e12y, L12, px, py)),
                    seg_d2_exact(v2x, v2y, e20x, e20y, L20, px, py));
                sd = -d2;
            }
        } else {
            const float d2 = fminf(fminf(
                seg_d2_exact(v0x, v0y, e01x, e01y, L01, px, py),
                seg_d2_exact(v1x, v1y, e12x, e12y, L12, px, py)),
                seg_d2_exact(v2x, v2y, e20x, e20y, L20, px, py));
            if (!(d2 <= BLUR)) continue;
            sd = d2;
        }

        if (z < bestZ) { bestZ = z; bestIdx = f; }

        float cz = z, cs = sd;
#pragma unroll
        for (int j2 = 0; j2 < KTOP; ++j2) {
            if (cz < tz[j2]) {
                const float oz = tz[j2], os = ts[j2];
                tz[j2] = cz; ts[j2] = cs; cz = oz; cs = os;
            }
        }
    }

    // ---- merge NW per-wave sorted top-K lists per pixel via LDS (R4-proven) ----
#pragma unroll
    for (int j = 0; j < KTOP; ++j) { sZ[w][lane][j] = tz[j]; sS[w][lane][j] = ts[j]; }
    sZ[w][lane][KTOP] = 3e38f;
    sBZ[w][lane] = bestZ;
    sBI[w][lane] = bestIdx;
    __syncthreads();

    if (threadIdx.x < 64) {
        const int p = threadIdx.x;
        float bz = sBZ[0][p]; int bi = sBI[0][p];
#pragma unroll
        for (int w2 = 1; w2 < NW; ++w2) {
            if (sBZ[w2][p] < bz) { bz = sBZ[w2][p]; bi = sBI[w2][p]; }
        }
        int ptr[NW];
#pragma unroll
        for (int w2 = 0; w2 < NW; ++w2) ptr[w2] = 0;
        float prod = 1.0f;
#pragma unroll
        for (int k = 0; k < KTOP; ++k) {
            float mz = 3e38f; int mw = -1;
#pragma unroll
            for (int w2 = 0; w2 < NW; ++w2) {
                const float zc = sZ[w2][p][ptr[w2]];
                if (zc < mz) { mz = zc; mw = w2; }
            }
            float sd = 3e38f;
#pragma unroll
            for (int w2 = 0; w2 < NW; ++w2) {
                if (w2 == mw) { sd = sS[w2][p][ptr[w2]]; ptr[w2]++; }
            }
            prod *= 1.0f / (1.0f + __expf(-sd * 1e4f));
        }
        const float alpha = 1.0f - prod;
        const int gx = (blockIdx.x << 3) + (p & 7);
        const int gy = (blockIdx.y << 3) + (p >> 3);
        out[(size_t)b * (SDIM * SDIM) + gy * SDIM + gx] = alpha;

        if (bi >= 0) {
            const int* fp = faces + ((size_t)b * NF + bi) * 3;
            float* vis = out + IMG_SZ;
            vis[b * NV + fp[0]] = 1.0f;
            vis[b * NV + fp[1]] = 1.0f;
            vis[b * NV + fp[2]] = 1.0f;
        }
    }
}

extern "C" void kernel_launch(void* const* d_in, const int* in_sizes, int n_in,
                              void* d_out, int out_size, void* d_ws, size_t ws_size,
                              hipStream_t stream)
{
    const float* verts = (const float*)d_in[0];
    const int*   faces = (const int*)d_in[1];
    float* out = (float*)d_out;
    float4* fdA = (float4*)d_ws;                                     // 320,000 B
    float*  fdB = (float*)((char*)d_ws + NB * NF * 32);              // 960,000 B
    float4* fdC = (float4*)((char*)d_ws + NB * NF * (32 + 96));     // 480,000 B

    const int total = NB * NV;   // 10046 >= NB*NF
    preprocess_kernel<<<dim3((total + 255) / 256), dim3(256), 0, stream>>>(verts, faces, fdA, fdB, fdC, out);
    raster_kernel<<<dim3(SDIM / 8, SDIM / 8, NB), dim3(64 * NW), 0, stream>>>(fdA, fdB, fdC, faces, out);
}